// Round 1
// baseline (34345.987 us; speedup 1.0000x reference)
//
#include <hip/hip_runtime.h>
#include <hip/hip_cooperative_groups.h>
#include <cstdint>
#include <cstddef>

namespace cg = cooperative_groups;

#define T_ 2048
#define N_ 64
#define L_ 300
#define V_ 35
#define E_ 256
#define H_ 512
#define KS_ 128

typedef __attribute__((ext_vector_type(8))) short short8;
typedef __attribute__((ext_vector_type(4))) float float4v;

struct Params {
    // inputs (setup_inputs order)
    const float *key, *values;
    const int *x_lens, *text;
    const float *emb_W;
    const float *W_ih1, *W_hh1, *b_ih1, *b_hh1;
    const float *W_ih2, *W_hh2, *b_ih2, *b_hh2;
    const float *W_ih3, *W_hh3, *b_ih3, *b_hh3;
    const float *b_out;
    // workspace
    unsigned short *Wih1b, *Whh1b, *Wih2b, *Whh2b, *Wih3b, *Whh3b, *embWb;
    float *b1, *b2, *b3;
    unsigned short *keyB, *valB;         // [n][t][k] bf16
    float *c1, *c2, *c3, *h3f;
    unsigned short *h1b0, *h1b1, *h2b0, *h2b1, *x1b;
    float *out;
};

__device__ __forceinline__ float b2f(unsigned short u) {
    unsigned int i = ((unsigned int)u) << 16;
    float f; __builtin_memcpy(&f, &i, 4); return f;
}
__device__ __forceinline__ unsigned short f2b(float f) {
    unsigned int i; __builtin_memcpy(&i, &f, 4);
    i += 0x7FFFu + ((i >> 16) & 1u);
    return (unsigned short)(i >> 16);
}
__device__ __forceinline__ float sigm(float x) { return 1.0f / (1.0f + __expf(-x)); }
__device__ __forceinline__ float tanh_(float x) {
    float e = __expf(2.0f * x);
    return 1.0f - 2.0f / (e + 1.0f);
}
__device__ __forceinline__ float wredmax(float v) {
#pragma unroll
    for (int o = 32; o > 0; o >>= 1) v = fmaxf(v, __shfl_down(v, o));
    return v;
}
__device__ __forceinline__ float wredsum(float v) {
#pragma unroll
    for (int o = 32; o > 0; o >>= 1) v += __shfl_down(v, o);
    return v;
}
__device__ __forceinline__ float dot8(short8 w8, float4v a, float4v b) {
    return b2f((unsigned short)w8[0]) * a[0] + b2f((unsigned short)w8[1]) * a[1]
         + b2f((unsigned short)w8[2]) * a[2] + b2f((unsigned short)w8[3]) * a[3]
         + b2f((unsigned short)w8[4]) * b[0] + b2f((unsigned short)w8[5]) * b[1]
         + b2f((unsigned short)w8[6]) * b[2] + b2f((unsigned short)w8[7]) * b[3];
}

struct SharedD {
    float h2r[512];
    float h3p[128];
    float g3[512];
    float h3s[128];
    float att[2048];
    float ctxp[32][128];
    float ctxf[128];
    float red[32];
    float lsum[35][8];
};
union SharedU {
    float gld[2][4][16][16];   // 8 KB gate exchange for LSTM1/2 epilogue
    SharedD d;                 // ~31 KB attention phase
};

// One LSTM layer (H_=512 outputs) computed by 64 WGs of 512 threads via MFMA.
// WG w: mt = w&3 (16-row m tile), ktp = w>>2 (pair of 16-wide hidden k tiles).
template <int KX>
__device__ __forceinline__ void lstm_layer(
    int wg, int tid,
    const unsigned short* __restrict__ xin,   // [64][KX] bf16
    const unsigned short* __restrict__ Wx,    // [2048][KX] bf16
    const unsigned short* __restrict__ hprev, // [64][512] bf16
    const unsigned short* __restrict__ Wh,    // [2048][512] bf16
    const float* __restrict__ bias,           // [2048] = b_ih+b_hh
    float* __restrict__ cstate,               // [64][512] f32
    unsigned short* __restrict__ hout,        // [64][512] bf16
    float (*gld)[4][16][16])
{
    const int lane = tid & 63, wv = tid >> 6;
    const int q = lane >> 4, l15 = lane & 15;
    const int mt = wg & 3, ktp = wg >> 2;
    const int kt = 2 * ktp + (wv & 1), tt = wv >> 1;  // tt = gate type 0..3 (i,f,g,o)
    const int col = tt * H_ + kt * 16 + l15;
    const int m = mt * 16 + l15;

    float4v acc = {0.f, 0.f, 0.f, 0.f};
    {
        const unsigned short* ar = xin + (size_t)m * KX + q * 8;
        const unsigned short* br = Wx + (size_t)col * KX + q * 8;
#pragma unroll
        for (int k0 = 0; k0 < KX; k0 += 32)
            acc = __builtin_amdgcn_mfma_f32_16x16x32_bf16(
                *(const short8*)(ar + k0), *(const short8*)(br + k0), acc, 0, 0, 0);
    }
    {
        const unsigned short* ar = hprev + (size_t)m * H_ + q * 8;
        const unsigned short* br = Wh + (size_t)col * H_ + q * 8;
#pragma unroll
        for (int k0 = 0; k0 < H_; k0 += 32)
            acc = __builtin_amdgcn_mfma_f32_16x16x32_bf16(
                *(const short8*)(ar + k0), *(const short8*)(br + k0), acc, 0, 0, 0);
    }
    // D layout: lane holds D[row=q*4+r][col=l15]; stash as [kt-sub][gate][kcol][mrow]
#pragma unroll
    for (int r = 0; r < 4; r++) gld[wv & 1][tt][l15][q * 4 + r] = acc[r];
    __syncthreads();
    {
        const int kt2 = tid >> 8, kk = (tid >> 4) & 15, mm = tid & 15;
        const int kg = (2 * ktp + kt2) * 16 + kk;   // hidden index 0..511
        const int m2 = mt * 16 + mm;
        float gi = gld[kt2][0][kk][mm] + bias[kg];
        float gf = gld[kt2][1][kk][mm] + bias[H_ + kg];
        float gg = gld[kt2][2][kk][mm] + bias[2 * H_ + kg];
        float go = gld[kt2][3][kk][mm] + bias[3 * H_ + kg];
        const size_t ix = (size_t)m2 * H_ + kg;
        float c = sigm(gf) * cstate[ix] + sigm(gi) * tanh_(gg);
        cstate[ix] = c;
        hout[ix] = f2b(sigm(go) * tanh_(c));
    }
}

__global__ __launch_bounds__(512) void decoder_main(Params p)
{
    cg::grid_group grid = cg::this_grid();
    __shared__ SharedU sm;
    const int wg = blockIdx.x;     // 0..63
    const int tid = threadIdx.x;   // 0..511
    const int lane = tid & 63, wv = tid >> 6;
    float* const attbase = p.out + (size_t)N_ * L_ * V_;

    for (int l = 0; l < L_; ++l) {
        const unsigned short* h1prev = (l & 1) ? p.h1b1 : p.h1b0;
        unsigned short* h1cur = (l & 1) ? p.h1b0 : p.h1b1;
        const unsigned short* h2prev = (l & 1) ? p.h2b1 : p.h2b0;
        unsigned short* h2cur = (l & 1) ? p.h2b0 : p.h2b1;

        // ---- Phase A: LSTM1  (input = [emb||ctx] in x1b) ----
        lstm_layer<E_ + KS_>(wg, tid, p.x1b, p.Wih1b, h1prev, p.Whh1b,
                             p.b1, p.c1, h1cur, sm.gld);
        grid.sync();

        // ---- Phase B: LSTM2 ----
        lstm_layer<H_>(wg, tid, h1cur, p.Wih2b, h2prev, p.Whh2b,
                       p.b2, p.c2, h2cur, sm.gld);
        grid.sync();

        // ---- Phase D: per-n LSTM3 + attention + logits (WG n = wg) ----
        {
            SharedD& sd = sm.d;
            const int n = wg;
            const int len = p.x_lens[n];

            // stage h2 (this step) and h3 (prev step) as f32 in LDS
            sd.h2r[tid] = b2f(h2cur[(size_t)n * H_ + tid]);
            if (tid < KS_) sd.h3p[tid] = p.h3f[n * KS_ + tid];
            __syncthreads();

            // LSTM3 gate pre-activations: thread = gate column (512)
            {
                float acc = p.b3[tid];
                const unsigned short* wr = p.Wih3b + (size_t)tid * H_;
#pragma unroll 4
                for (int k0 = 0; k0 < H_; k0 += 8) {
                    short8 w8 = *(const short8*)(wr + k0);
                    const float4v* hv = (const float4v*)(sd.h2r + k0);
                    acc += dot8(w8, hv[0], hv[1]);
                }
                const unsigned short* wr2 = p.Whh3b + (size_t)tid * KS_;
#pragma unroll 4
                for (int k0 = 0; k0 < KS_; k0 += 8) {
                    short8 w8 = *(const short8*)(wr2 + k0);
                    const float4v* hv = (const float4v*)(sd.h3p + k0);
                    acc += dot8(w8, hv[0], hv[1]);
                }
                sd.g3[tid] = acc;
            }
            __syncthreads();
            if (tid < KS_) {
                float gi = sigm(sd.g3[tid]);
                float gf = sigm(sd.g3[KS_ + tid]);
                float gg = tanh_(sd.g3[2 * KS_ + tid]);
                float go = sigm(sd.g3[3 * KS_ + tid]);
                float c = gf * p.c3[n * KS_ + tid] + gi * gg;
                p.c3[n * KS_ + tid] = c;
                float h = go * tanh_(c);
                sd.h3s[tid] = h;
                p.h3f[n * KS_ + tid] = h;   // for next step's h3p
            }
            __syncthreads();

            // energy[t] = key[n][t][:] . h3 ; thread owns t = tid + 512*i
            float e4[4];
            const unsigned short* kbase = p.keyB + (size_t)n * T_ * KS_;
#pragma unroll
            for (int i = 0; i < 4; i++) {
                int t = tid + 512 * i;
                float e = -1e30f;
                if (t < len) {
                    const unsigned short* kr = kbase + (size_t)t * KS_;
                    const float4v* hv = (const float4v*)sd.h3s;
                    float s = 0.f;
#pragma unroll
                    for (int kk = 0; kk < 16; kk++) {
                        short8 k8 = *(const short8*)(kr + kk * 8);
                        s += dot8(k8, hv[2 * kk], hv[2 * kk + 1]);
                    }
                    e = s;
                }
                e4[i] = e;
            }
            // softmax (valid t only; masked = exact 0, region pre-zeroed)
            float mloc = fmaxf(fmaxf(e4[0], e4[1]), fmaxf(e4[2], e4[3]));
            mloc = wredmax(mloc);
            if (lane == 0) sd.red[wv] = mloc;
            __syncthreads();
            if (tid == 0) {
                float M = sd.red[0];
                for (int i = 1; i < 8; i++) M = fmaxf(M, sd.red[i]);
                sd.red[16] = M;
            }
            __syncthreads();
            const float M = sd.red[16];
            float pp[4]; float ps = 0.f;
#pragma unroll
            for (int i = 0; i < 4; i++) {
                int t = tid + 512 * i;
                float v = (t < len) ? __expf(e4[i] - M) : 0.f;
                pp[i] = v; ps += v;
                sd.att[t] = v;
            }
            ps = wredsum(ps);
            if (lane == 0) sd.red[wv] = ps;
            __syncthreads();
            if (tid == 0) {
                float s = 0.f;
                for (int i = 0; i < 8; i++) s += sd.red[i];
                sd.red[17] = s;
            }
            __syncthreads();
            const float rL = 1.0f / sd.red[17];
            {
                float* attout = attbase + ((size_t)n * L_ + l) * T_;
#pragma unroll
                for (int i = 0; i < 4; i++) {
                    int t = tid + 512 * i;
                    if (t < len) attout[t] = pp[i] * rL;
                }
            }
            // ctx[e] = sum_t p[t]*values[n][t][e] (scale by rL at the end)
            {
                const int tg = tid >> 4, e8 = tid & 15;
                float a8[8] = {0, 0, 0, 0, 0, 0, 0, 0};
                const unsigned short* vbase = p.valB + (size_t)n * T_ * KS_ + e8 * 8;
                for (int t = tg; t < len; t += 32) {
                    float w = sd.att[t];
                    short8 v8 = *(const short8*)(vbase + (size_t)t * KS_);
                    a8[0] += w * b2f((unsigned short)v8[0]);
                    a8[1] += w * b2f((unsigned short)v8[1]);
                    a8[2] += w * b2f((unsigned short)v8[2]);
                    a8[3] += w * b2f((unsigned short)v8[3]);
                    a8[4] += w * b2f((unsigned short)v8[4]);
                    a8[5] += w * b2f((unsigned short)v8[5]);
                    a8[6] += w * b2f((unsigned short)v8[6]);
                    a8[7] += w * b2f((unsigned short)v8[7]);
                }
#pragma unroll
                for (int j = 0; j < 8; j++) sd.ctxp[tg][e8 * 8 + j] = a8[j];
            }
            __syncthreads();
            if (tid < KS_) {
                float s = 0.f;
#pragma unroll 8
                for (int g2 = 0; g2 < 32; g2++) s += sd.ctxp[g2][tid];
                s *= rL;
                sd.ctxf[tid] = s;
                p.x1b[(size_t)n * (E_ + KS_) + E_ + tid] = f2b(s);  // ctx -> next LSTM1 input
            }
            __syncthreads();
            // logits = [h3||ctx] @ emb_W^T + b_out  (fp32 weights for accuracy)
            if (tid < V_ * 8) {
                const int v = tid >> 3, oc = tid & 7;
                const float* er = p.emb_W + (size_t)v * E_ + oc * 32;
                const float* src = (oc < 4) ? (sd.h3s + oc * 32) : (sd.ctxf + oc * 32 - 128);
                float s = 0.f;
#pragma unroll
                for (int j = 0; j < 32; j++) s += src[j] * er[j];
                sd.lsum[v][oc] = s;
            }
            // next step's embedding into x1b
            if (l + 1 < L_ && tid < E_) {
                int row = p.text[n * L_ + l + 1];
                p.x1b[(size_t)n * (E_ + KS_) + tid] = p.embWb[(size_t)row * E_ + tid];
            }
            __syncthreads();
            if (tid < V_) {
                float s = p.b_out[tid];
#pragma unroll
                for (int j = 0; j < 8; j++) s += sd.lsum[tid][j];
                p.out[((size_t)n * L_ + l) * V_ + tid] = s;
            }
        }
        grid.sync();
    }
}

// ---------------- setup kernels ----------------
__global__ void setup_weights(Params p)
{
    size_t stride = (size_t)gridDim.x * blockDim.x;
    for (size_t i = (size_t)blockIdx.x * blockDim.x + threadIdx.x; i < 1048576; i += stride) {
        if (i < 786432) p.Wih1b[i] = f2b(p.W_ih1[i]);
        p.Whh1b[i] = f2b(p.W_hh1[i]);
        p.Wih2b[i] = f2b(p.W_ih2[i]);
        p.Whh2b[i] = f2b(p.W_hh2[i]);
        if (i < 262144) p.Wih3b[i] = f2b(p.W_ih3[i]);
        if (i < 65536)  p.Whh3b[i] = f2b(p.W_hh3[i]);
        if (i < 8960)   p.embWb[i] = f2b(p.emb_W[i]);
        if (i < 2048) {
            p.b1[i] = p.b_ih1[i] + p.b_hh1[i];
            p.b2[i] = p.b_ih2[i] + p.b_hh2[i];
        }
        if (i < 512) p.b3[i] = p.b_ih3[i] + p.b_hh3[i];
    }
}

__global__ void setup_kv(Params p)
{
    size_t stride = (size_t)gridDim.x * blockDim.x;
    const size_t total = (size_t)T_ * N_ * KS_;
    for (size_t idx = (size_t)blockIdx.x * blockDim.x + threadIdx.x; idx < total; idx += stride) {
        int t = (int)(idx >> 13);          // / (64*128)
        int rem = (int)(idx & 8191);
        int n = rem >> 7, k = rem & 127;
        size_t dst = ((size_t)n * T_ + t) * KS_ + k;
        p.keyB[dst] = f2b(p.key[idx]);
        p.valB[dst] = f2b(p.values[idx]);
    }
}

__global__ void setup_x1(Params p)
{
    int n = blockIdx.x, tid = threadIdx.x;   // 64 x 256
    int row = p.text[n * L_];
    p.x1b[(size_t)n * (E_ + KS_) + tid] = p.embWb[(size_t)row * E_ + tid];
}

// ---------------- host ----------------
extern "C" void kernel_launch(void* const* d_in, const int* in_sizes, int n_in,
                              void* d_out, int out_size, void* d_ws, size_t ws_size,
                              hipStream_t stream)
{
    (void)in_sizes; (void)n_in; (void)out_size; (void)ws_size;
    Params p;
    p.key    = (const float*)d_in[0];
    p.values = (const float*)d_in[1];
    p.x_lens = (const int*)d_in[2];
    p.text   = (const int*)d_in[3];
    p.emb_W  = (const float*)d_in[4];
    p.W_ih1  = (const float*)d_in[5];
    p.W_hh1  = (const float*)d_in[6];
    p.b_ih1  = (const float*)d_in[7];
    p.b_hh1  = (const float*)d_in[8];
    p.W_ih2  = (const float*)d_in[9];
    p.W_hh2  = (const float*)d_in[10];
    p.b_ih2  = (const float*)d_in[11];
    p.b_hh2  = (const float*)d_in[12];
    p.W_ih3  = (const float*)d_in[13];
    p.W_hh3  = (const float*)d_in[14];
    p.b_ih3  = (const float*)d_in[15];
    p.b_hh3  = (const float*)d_in[16];
    p.b_out  = (const float*)d_in[17];
    p.out    = (float*)d_out;

    char* w = (char*)d_ws;
    auto alloc = [&](size_t bytes) -> char* {
        char* r = w;
        w += (bytes + 255) & ~(size_t)255;
        return r;
    };
    p.Wih1b = (unsigned short*)alloc((size_t)786432 * 2);
    p.Whh1b = (unsigned short*)alloc((size_t)1048576 * 2);
    p.Wih2b = (unsigned short*)alloc((size_t)1048576 * 2);
    p.Whh2b = (unsigned short*)alloc((size_t)1048576 * 2);
    p.Wih3b = (unsigned short*)alloc((size_t)262144 * 2);
    p.Whh3b = (unsigned short*)alloc((size_t)65536 * 2);
    p.embWb = (unsigned short*)alloc((size_t)8960 * 2);
    p.b1 = (float*)alloc(2048 * 4);
    p.b2 = (float*)alloc(2048 * 4);
    p.b3 = (float*)alloc(512 * 4);
    p.keyB = (unsigned short*)alloc((size_t)16777216 * 2);
    p.valB = (unsigned short*)alloc((size_t)16777216 * 2);
    char* zstart = w;
    p.c1  = (float*)alloc((size_t)N_ * H_ * 4);
    p.c2  = (float*)alloc((size_t)N_ * H_ * 4);
    p.c3  = (float*)alloc((size_t)N_ * KS_ * 4);
    p.h3f = (float*)alloc((size_t)N_ * KS_ * 4);
    p.h1b0 = (unsigned short*)alloc((size_t)N_ * H_ * 2);
    p.h1b1 = (unsigned short*)alloc((size_t)N_ * H_ * 2);
    p.h2b0 = (unsigned short*)alloc((size_t)N_ * H_ * 2);
    p.h2b1 = (unsigned short*)alloc((size_t)N_ * H_ * 2);
    p.x1b  = (unsigned short*)alloc((size_t)N_ * (E_ + KS_) * 2);
    size_t zbytes = (size_t)(w - zstart);

    // zero states + x1 (ctx part), zero the att output region (masked slots stay 0)
    hipMemsetAsync(zstart, 0, zbytes, stream);
    hipMemsetAsync((char*)d_out + (size_t)N_ * L_ * V_ * 4, 0,
                   (size_t)N_ * L_ * T_ * 4, stream);

    setup_weights<<<dim3(256), dim3(256), 0, stream>>>(p);
    setup_kv<<<dim3(2048), dim3(256), 0, stream>>>(p);
    setup_x1<<<dim3(64), dim3(256), 0, stream>>>(p);

    void* args[] = { (void*)&p };
    hipLaunchCooperativeKernel((void*)decoder_main, dim3(64), dim3(512), args, 0, stream);
}